// Round 1
// baseline (25.149 us; speedup 1.0000x reference)
//
#include <hip/hip_runtime.h>

// PointRend-style head:
//   points = top-48-uncertainty(over_generation) ++ coverage   -> [8,64,2]
//   rend   = w @ concat(bilinear(out,points), bilinear(res2,points)) + b -> [8,2,64]
// Output layout: d_out = [rend (8*2*64=1024 floats)][points (8*64*2=1024 floats)]
// Input x (d_in[0]) is shape-only in the reference; never read.

__device__ __forceinline__ void bilin_setup(float px, float py, int H, int W,
                                            int idx[4], float cw[4]) {
    // Replicates the reference op order exactly:
    // g = 2p-1; x = ((g+1)*W - 1)*0.5
    float gx = 2.0f * px - 1.0f;
    float gy = 2.0f * py - 1.0f;
    float x = ((gx + 1.0f) * (float)W - 1.0f) * 0.5f;
    float y = ((gy + 1.0f) * (float)H - 1.0f) * 0.5f;
    float x0 = floorf(x), y0 = floorf(y);
    float wx1 = x - x0, wy1 = y - y0;
    float wxs[2] = {1.0f - wx1, wx1};
    float wys[2] = {1.0f - wy1, wy1};
    float xs[2] = {x0, x0 + 1.0f};
    float ys[2] = {y0, y0 + 1.0f};
#pragma unroll
    for (int dy = 0; dy < 2; ++dy) {
#pragma unroll
        for (int dx = 0; dx < 2; ++dx) {
            float xf = xs[dx], yf = ys[dy];
            bool valid = (xf >= 0.0f) && (xf <= (float)(W - 1)) &&
                         (yf >= 0.0f) && (yf <= (float)(H - 1));
            float xc = fminf(fmaxf(xf, 0.0f), (float)(W - 1));
            float yc = fminf(fmaxf(yf, 0.0f), (float)(H - 1));
            int xi = (int)xc, yi = (int)yc;
            idx[dy * 2 + dx] = yi * W + xi;
            // reference: (v * valid) * (wy * wx); valid mult is exact (0/1)
            cw[dy * 2 + dx] = valid ? (wys[dy] * wxs[dx]) : 0.0f;
        }
    }
}

// One block per batch. Compute uncertainty for 192 candidates, stable top-48
// (rank = #{j : u[j] > u[i] || (u[j]==u[i] && j<i)}), emit points in
// descending-uncertainty order (matches jax.lax.top_k), append coverage.
__global__ void k_points(const float* __restrict__ outm,   // [8,2,64,64]
                         const float* __restrict__ og,     // [8,192,2]
                         const float* __restrict__ cov,    // [8,16,2]
                         float* __restrict__ points) {     // [8,64,2]
    const int b = blockIdx.x;
    const int t = threadIdx.x;
    __shared__ float u[192];
    if (t < 192) {
        float px = og[(b * 192 + t) * 2 + 0];
        float py = og[(b * 192 + t) * 2 + 1];
        int idx[4];
        float cw[4];
        bilin_setup(px, py, 64, 64, idx, cw);
        const float* c0 = outm + ((size_t)b * 2 + 0) * 4096;
        const float* c1 = outm + ((size_t)b * 2 + 1) * 4096;
        // mask_sorted: ch0 = per-pixel max, ch1 = per-pixel min
        float s0 = 0.0f, s1 = 0.0f;
#pragma unroll
        for (int k = 0; k < 4; ++k) {
            float a = c0[idx[k]];
            float d = c1[idx[k]];
            s0 += fmaxf(a, d) * cw[k];
            s1 += fminf(a, d) * cw[k];
        }
        u[t] = s1 - s0;  // uncertainty = -(max_samp - min_samp)
    }
    __syncthreads();
    if (t < 192) {
        float ui = u[t];
        int rank = 0;
        for (int j = 0; j < 192; ++j) {
            float uj = u[j];
            if (uj > ui || (uj == ui && j < t)) rank++;
        }
        if (rank < 48) {
            points[b * 128 + rank * 2 + 0] = og[(b * 192 + t) * 2 + 0];
            points[b * 128 + rank * 2 + 1] = og[(b * 192 + t) * 2 + 1];
        }
    }
    if (t < 16) {
        points[b * 128 + (48 + t) * 2 + 0] = cov[(b * 16 + t) * 2 + 0];
        points[b * 128 + (48 + t) * 2 + 1] = cov[(b * 16 + t) * 2 + 1];
    }
}

// One block per (b, n). 256 threads x 2 channels of res2 each; fused matvec
// against w[2,514]; thread 0 adds the 2 coarse channels + bias.
__global__ void k_render(const float* __restrict__ outm,   // [8,2,64,64]
                         const float* __restrict__ res2,   // [8,512,256,256]
                         const float* __restrict__ w,      // [2,514]
                         const float* __restrict__ bias,   // [2]
                         const float* __restrict__ points, // [8,64,2]
                         float* __restrict__ rend) {       // [8,2,64]
    const int b = blockIdx.x >> 6;
    const int n = blockIdx.x & 63;
    const int t = threadIdx.x;
    const float px = points[b * 128 + n * 2 + 0];
    const float py = points[b * 128 + n * 2 + 1];
    int idx[4];
    float cw[4];
    bilin_setup(px, py, 256, 256, idx, cw);
    float acc0 = 0.0f, acc1 = 0.0f;
#pragma unroll
    for (int cc = 0; cc < 2; ++cc) {
        int c = t + cc * 256;
        const float* base = res2 + ((size_t)b * 512 + c) * 65536;
        float f = base[idx[0]] * cw[0] + base[idx[1]] * cw[1] +
                  base[idx[2]] * cw[2] + base[idx[3]] * cw[3];
        acc0 += w[2 + c] * f;        // w[0][2+c]
        acc1 += w[514 + 2 + c] * f;  // w[1][2+c]
    }
    __shared__ float s0[256], s1[256];
    s0[t] = acc0;
    s1[t] = acc1;
    __syncthreads();
    for (int off = 128; off > 0; off >>= 1) {
        if (t < off) {
            s0[t] += s0[t + off];
            s1[t] += s1[t + off];
        }
        __syncthreads();
    }
    if (t == 0) {
        int idc[4];
        float cwc[4];
        bilin_setup(px, py, 64, 64, idc, cwc);
        const float* c0p = outm + ((size_t)b * 2 + 0) * 4096;
        const float* c1p = outm + ((size_t)b * 2 + 1) * 4096;
        float coarse0 = c0p[idc[0]] * cwc[0] + c0p[idc[1]] * cwc[1] +
                        c0p[idc[2]] * cwc[2] + c0p[idc[3]] * cwc[3];
        float coarse1 = c1p[idc[0]] * cwc[0] + c1p[idc[1]] * cwc[1] +
                        c1p[idc[2]] * cwc[2] + c1p[idc[3]] * cwc[3];
        float r0 = w[0] * coarse0 + w[1] * coarse1 + s0[0] + bias[0];
        float r1 = w[514] * coarse0 + w[514 + 1] * coarse1 + s1[0] + bias[1];
        rend[((size_t)b * 2 + 0) * 64 + n] = r0;
        rend[((size_t)b * 2 + 1) * 64 + n] = r1;
    }
}

extern "C" void kernel_launch(void* const* d_in, const int* in_sizes, int n_in,
                              void* d_out, int out_size, void* d_ws, size_t ws_size,
                              hipStream_t stream) {
    // inputs: 0:x (unused), 1:res2, 2:out, 3:over_generation, 4:coverage, 5:w, 6:b
    const float* res2 = (const float*)d_in[1];
    const float* outm = (const float*)d_in[2];
    const float* og   = (const float*)d_in[3];
    const float* cov  = (const float*)d_in[4];
    const float* w    = (const float*)d_in[5];
    const float* bias = (const float*)d_in[6];

    float* rend = (float*)d_out;          // [8,2,64] = 1024 floats
    float* points = rend + 1024;          // [8,64,2] = 1024 floats

    k_points<<<8, 256, 0, stream>>>(outm, og, cov, points);
    k_render<<<512, 256, 0, stream>>>(outm, res2, w, bias, points, rend);
}

// Round 2
// 21.190 us; speedup vs baseline: 1.1869x; 1.1869x over previous
//
#include <hip/hip_runtime.h>

// PointRend-style head, fully fused into ONE kernel launch.
//   points = top-48-uncertainty(over_generation) ++ coverage   -> [8,64,2]
//   rend   = w @ concat(bilinear(out,points), bilinear(res2,points)) + b -> [8,2,64]
// Output layout: d_out = [rend (1024 floats)][points (1024 floats)]
// Input x (d_in[0]) is shape-only in the reference; never read.
//
// Block (b,n) recomputes the top-k selection for its own point (cheap,
// L2-resident out-map) -> no inter-kernel dependency, single launch.

__device__ __forceinline__ void bilin_setup(float px, float py, int H, int W,
                                            int idx[4], float cw[4]) {
    // Replicates the reference op order exactly.
    float gx = 2.0f * px - 1.0f;
    float gy = 2.0f * py - 1.0f;
    float x = ((gx + 1.0f) * (float)W - 1.0f) * 0.5f;
    float y = ((gy + 1.0f) * (float)H - 1.0f) * 0.5f;
    float x0 = floorf(x), y0 = floorf(y);
    float wx1 = x - x0, wy1 = y - y0;
    float wxs[2] = {1.0f - wx1, wx1};
    float wys[2] = {1.0f - wy1, wy1};
    float xs[2] = {x0, x0 + 1.0f};
    float ys[2] = {y0, y0 + 1.0f};
#pragma unroll
    for (int dy = 0; dy < 2; ++dy) {
#pragma unroll
        for (int dx = 0; dx < 2; ++dx) {
            float xf = xs[dx], yf = ys[dy];
            bool valid = (xf >= 0.0f) && (xf <= (float)(W - 1)) &&
                         (yf >= 0.0f) && (yf <= (float)(H - 1));
            float xc = fminf(fmaxf(xf, 0.0f), (float)(W - 1));
            float yc = fminf(fmaxf(yf, 0.0f), (float)(H - 1));
            int xi = (int)xc, yi = (int)yc;
            idx[dy * 2 + dx] = yi * W + xi;
            cw[dy * 2 + dx] = valid ? (wys[dy] * wxs[dx]) : 0.0f;
        }
    }
}

__global__ __launch_bounds__(512) void k_fused(
    const float* __restrict__ outm,   // [8,2,64,64]
    const float* __restrict__ res2,   // [8,512,256,256]
    const float* __restrict__ w,      // [2,514]
    const float* __restrict__ bias,   // [2]
    const float* __restrict__ og,     // [8,192,2]
    const float* __restrict__ cov,    // [8,16,2]
    float* __restrict__ rend,         // [8,2,64]
    float* __restrict__ points) {     // [8,64,2]
    const int b = blockIdx.x >> 6;
    const int n = blockIdx.x & 63;
    const int t = threadIdx.x;

    __shared__ float u[192];
    __shared__ float sp[2];

    if (n < 48) {
        // Phase 1: uncertainty for all 192 candidates of batch b.
        if (t < 192) {
            float2 p = ((const float2*)og)[b * 192 + t];
            int idx[4];
            float cw[4];
            bilin_setup(p.x, p.y, 64, 64, idx, cw);
            const float* c0 = outm + (size_t)b * 2 * 4096;
            const float* c1 = c0 + 4096;
            float s0 = 0.0f, s1 = 0.0f;
#pragma unroll
            for (int k = 0; k < 4; ++k) {
                float a = c0[idx[k]];
                float d = c1[idx[k]];
                s0 += fmaxf(a, d) * cw[k];  // mask_sorted ch0 = per-pixel max
                s1 += fminf(a, d) * cw[k];  // mask_sorted ch1 = per-pixel min
            }
            u[t] = s1 - s0;  // uncertainty = -(max_samp - min_samp)
        }
        __syncthreads();
        // Phase 2: which candidate has rank n? (lax.top_k order: descending
        // value, ties -> lower index first; ranks are unique)
        if (t < 192) {
            float ui = u[t];
            int rank = 0;
            for (int j = 0; j < 192; ++j) {
                float uj = u[j];
                rank += (uj > ui || (uj == ui && j < t)) ? 1 : 0;
            }
            if (rank == n) {
                float2 p = ((const float2*)og)[b * 192 + t];
                sp[0] = p.x;
                sp[1] = p.y;
            }
        }
        __syncthreads();
    } else {
        if (t == 0) {
            float2 p = ((const float2*)cov)[b * 16 + (n - 48)];
            sp[0] = p.x;
            sp[1] = p.y;
        }
        __syncthreads();
    }

    const float px = sp[0], py = sp[1];
    if (t == 0) {
        points[b * 128 + n * 2 + 0] = px;
        points[b * 128 + n * 2 + 1] = py;
    }

    // Phase 3: res2 gather, 1 channel per thread, fused matvec.
    int idx[4];
    float cw[4];
    bilin_setup(px, py, 256, 256, idx, cw);
    const int c = t;  // 512 channels
    const float* base = res2 + ((size_t)b * 512 + c) * 65536;
    float f = base[idx[0]] * cw[0] + base[idx[1]] * cw[1] +
              base[idx[2]] * cw[2] + base[idx[3]] * cw[3];
    float acc0 = w[2 + c] * f;        // w[0][2+c]
    float acc1 = w[516 + c] * f;      // w[1][2+c]

    // wave (64-lane) shuffle reduce, then 8 partials via LDS
#pragma unroll
    for (int off = 32; off > 0; off >>= 1) {
        acc0 += __shfl_down(acc0, off, 64);
        acc1 += __shfl_down(acc1, off, 64);
    }
    __shared__ float r0s[8], r1s[8];
    const int wid = t >> 6, lane = t & 63;
    if (lane == 0) {
        r0s[wid] = acc0;
        r1s[wid] = acc1;
    }
    __syncthreads();
    if (t == 0) {
        float a0 = 0.0f, a1 = 0.0f;
#pragma unroll
        for (int i = 0; i < 8; ++i) {
            a0 += r0s[i];
            a1 += r1s[i];
        }
        int idc[4];
        float cwc[4];
        bilin_setup(px, py, 64, 64, idc, cwc);
        const float* c0p = outm + (size_t)b * 2 * 4096;
        const float* c1p = c0p + 4096;
        float coarse0 = c0p[idc[0]] * cwc[0] + c0p[idc[1]] * cwc[1] +
                        c0p[idc[2]] * cwc[2] + c0p[idc[3]] * cwc[3];
        float coarse1 = c1p[idc[0]] * cwc[0] + c1p[idc[1]] * cwc[1] +
                        c1p[idc[2]] * cwc[2] + c1p[idc[3]] * cwc[3];
        rend[((size_t)b * 2 + 0) * 64 + n] = w[0] * coarse0 + w[1] * coarse1 + a0 + bias[0];
        rend[((size_t)b * 2 + 1) * 64 + n] = w[514] * coarse0 + w[515] * coarse1 + a1 + bias[1];
    }
}

extern "C" void kernel_launch(void* const* d_in, const int* in_sizes, int n_in,
                              void* d_out, int out_size, void* d_ws, size_t ws_size,
                              hipStream_t stream) {
    // inputs: 0:x (unused), 1:res2, 2:out, 3:over_generation, 4:coverage, 5:w, 6:b
    const float* res2 = (const float*)d_in[1];
    const float* outm = (const float*)d_in[2];
    const float* og   = (const float*)d_in[3];
    const float* cov  = (const float*)d_in[4];
    const float* w    = (const float*)d_in[5];
    const float* bias = (const float*)d_in[6];

    float* rend = (float*)d_out;    // [8,2,64] = 1024 floats
    float* points = rend + 1024;    // [8,64,2] = 1024 floats

    k_fused<<<512, 512, 0, stream>>>(outm, res2, w, bias, og, cov, rend, points);
}

// Round 3
// 21.018 us; speedup vs baseline: 1.1966x; 1.0082x over previous
//
#include <hip/hip_runtime.h>

// PointRend-style head, fully fused into ONE kernel launch.
//   points = top-48-uncertainty(over_generation) ++ coverage   -> [8,64,2]
//   rend   = w @ concat(bilinear(out,points), bilinear(res2,points)) + b -> [8,2,64]
// Output layout: d_out = [rend (1024 floats)][points (1024 floats)]
// Input x (d_in[0]) is shape-only in the reference; never read.
//
// Block (b,n): 1024 threads. Selection blocks (n<48) recompute the top-k
// ranking for batch b (L2-resident out-map, ~1us). Gather phase: thread t
// handles channel c=t&511, row-pair half=t>>9 (2 loads from one row of the
// 256x256 map -> usually one 64B line). 16 waves/block, 2 blocks/CU
// -> 32 waves/CU (100% occupancy) for maximum memory-level parallelism.

__device__ __forceinline__ void bilin_setup(float px, float py, int H, int W,
                                            int idx[4], float cw[4]) {
    // Replicates the reference op order exactly.
    float gx = 2.0f * px - 1.0f;
    float gy = 2.0f * py - 1.0f;
    float x = ((gx + 1.0f) * (float)W - 1.0f) * 0.5f;
    float y = ((gy + 1.0f) * (float)H - 1.0f) * 0.5f;
    float x0 = floorf(x), y0 = floorf(y);
    float wx1 = x - x0, wy1 = y - y0;
    float wxs[2] = {1.0f - wx1, wx1};
    float wys[2] = {1.0f - wy1, wy1};
    float xs[2] = {x0, x0 + 1.0f};
    float ys[2] = {y0, y0 + 1.0f};
#pragma unroll
    for (int dy = 0; dy < 2; ++dy) {
#pragma unroll
        for (int dx = 0; dx < 2; ++dx) {
            float xf = xs[dx], yf = ys[dy];
            bool valid = (xf >= 0.0f) && (xf <= (float)(W - 1)) &&
                         (yf >= 0.0f) && (yf <= (float)(H - 1));
            float xc = fminf(fmaxf(xf, 0.0f), (float)(W - 1));
            float yc = fminf(fmaxf(yf, 0.0f), (float)(H - 1));
            int xi = (int)xc, yi = (int)yc;
            idx[dy * 2 + dx] = yi * W + xi;
            cw[dy * 2 + dx] = valid ? (wys[dy] * wxs[dx]) : 0.0f;
        }
    }
}

__global__ __launch_bounds__(1024, 8) void k_fused(
    const float* __restrict__ outm,   // [8,2,64,64]
    const float* __restrict__ res2,   // [8,512,256,256]
    const float* __restrict__ w,      // [2,514]
    const float* __restrict__ bias,   // [2]
    const float* __restrict__ og,     // [8,192,2]
    const float* __restrict__ cov,    // [8,16,2]
    float* __restrict__ rend,         // [8,2,64]
    float* __restrict__ points) {     // [8,64,2]
    const int b = blockIdx.x >> 6;
    const int n = blockIdx.x & 63;
    const int t = threadIdx.x;

    __shared__ float u[192];
    __shared__ float sp[2];

    if (n < 48) {
        // Phase 1: uncertainty for all 192 candidates of batch b.
        if (t < 192) {
            float2 p = ((const float2*)og)[b * 192 + t];
            int idx[4];
            float cw[4];
            bilin_setup(p.x, p.y, 64, 64, idx, cw);
            const float* c0 = outm + (size_t)b * 2 * 4096;
            const float* c1 = c0 + 4096;
            float s0 = 0.0f, s1 = 0.0f;
#pragma unroll
            for (int k = 0; k < 4; ++k) {
                float a = c0[idx[k]];
                float d = c1[idx[k]];
                s0 += fmaxf(a, d) * cw[k];  // mask_sorted ch0 = per-pixel max
                s1 += fminf(a, d) * cw[k];  // mask_sorted ch1 = per-pixel min
            }
            u[t] = s1 - s0;  // uncertainty = -(max_samp - min_samp)
        }
        __syncthreads();
        // Phase 2: which candidate has rank n? (lax.top_k order: descending
        // value, ties -> lower index first; ranks are unique)
        if (t < 192) {
            float ui = u[t];
            int rank = 0;
            for (int j = 0; j < 192; ++j) {
                float uj = u[j];
                rank += (uj > ui || (uj == ui && j < t)) ? 1 : 0;
            }
            if (rank == n) {
                float2 p = ((const float2*)og)[b * 192 + t];
                sp[0] = p.x;
                sp[1] = p.y;
            }
        }
        __syncthreads();
    } else {
        if (t == 0) {
            float2 p = ((const float2*)cov)[b * 16 + (n - 48)];
            sp[0] = p.x;
            sp[1] = p.y;
        }
        __syncthreads();
    }

    const float px = sp[0], py = sp[1];
    if (t == 1) {
        points[b * 128 + n * 2 + 0] = px;
        points[b * 128 + n * 2 + 1] = py;
    }

    // Coarse sample on thread 0, issued concurrently with the gather below.
    float coarse0 = 0.0f, coarse1 = 0.0f;
    if (t == 0) {
        int idc[4];
        float cwc[4];
        bilin_setup(px, py, 64, 64, idc, cwc);
        const float* c0p = outm + (size_t)b * 2 * 4096;
        const float* c1p = c0p + 4096;
        coarse0 = c0p[idc[0]] * cwc[0] + c0p[idc[1]] * cwc[1] +
                  c0p[idc[2]] * cwc[2] + c0p[idc[3]] * cwc[3];
        coarse1 = c1p[idc[0]] * cwc[0] + c1p[idc[1]] * cwc[1] +
                  c1p[idc[2]] * cwc[2] + c1p[idc[3]] * cwc[3];
    }

    // Gather: channel c = t&511, row-pair half = t>>9 (2 loads, one row).
    int idx[4];
    float cw[4];
    bilin_setup(px, py, 256, 256, idx, cw);
    const int c = t & 511;
    const int half = t >> 9;
    const float* base = res2 + ((size_t)b * 512 + c) * 65536;
    float f = base[idx[2 * half]] * cw[2 * half] +
              base[idx[2 * half + 1]] * cw[2 * half + 1];
    float acc0 = w[2 + c] * f;        // w[0][2+c]
    float acc1 = w[516 + c] * f;      // w[1][2+c]

    // wave (64-lane) shuffle reduce, then 16 partials via LDS
#pragma unroll
    for (int off = 32; off > 0; off >>= 1) {
        acc0 += __shfl_down(acc0, off, 64);
        acc1 += __shfl_down(acc1, off, 64);
    }
    __shared__ float r0s[16], r1s[16];
    const int wid = t >> 6, lane = t & 63;
    if (lane == 0) {
        r0s[wid] = acc0;
        r1s[wid] = acc1;
    }
    __syncthreads();
    if (t == 0) {
        float a0 = 0.0f, a1 = 0.0f;
#pragma unroll
        for (int i = 0; i < 16; ++i) {
            a0 += r0s[i];
            a1 += r1s[i];
        }
        rend[((size_t)b * 2 + 0) * 64 + n] = w[0] * coarse0 + w[1] * coarse1 + a0 + bias[0];
        rend[((size_t)b * 2 + 1) * 64 + n] = w[514] * coarse0 + w[515] * coarse1 + a1 + bias[1];
    }
}

extern "C" void kernel_launch(void* const* d_in, const int* in_sizes, int n_in,
                              void* d_out, int out_size, void* d_ws, size_t ws_size,
                              hipStream_t stream) {
    // inputs: 0:x (unused), 1:res2, 2:out, 3:over_generation, 4:coverage, 5:w, 6:b
    const float* res2 = (const float*)d_in[1];
    const float* outm = (const float*)d_in[2];
    const float* og   = (const float*)d_in[3];
    const float* cov  = (const float*)d_in[4];
    const float* w    = (const float*)d_in[5];
    const float* bias = (const float*)d_in[6];

    float* rend = (float*)d_out;    // [8,2,64] = 1024 floats
    float* points = rend + 1024;    // [8,64,2] = 1024 floats

    k_fused<<<512, 1024, 0, stream>>>(outm, res2, w, bias, og, cov, rend, points);
}